// Round 6
// baseline (350.000 us; speedup 1.0000x reference)
//
#include <hip/hip_runtime.h>

// SemanticCaps dynamic routing, fp32. B=128, J=10, K=1152, M=16, I=8.
// R10: single persistent cooperative kernel with HAND-ROLLED grid barriers.
// R9 analysis: 137.6 = 41 (harness poison fill) + ~23 (kernel work) + ~70
// (6 dispatch boundaries x ~10-12 µs launch overhead). cg::grid.sync() is
// disqualified (R3: ~55 µs/sync, 2560 spinning waves, 192 MB poll traffic);
// this barrier has ONE poller per block (256 total) with s_sleep backoff,
// single-use {cnt,gen} pairs, agent-scope acq/rel + __threadfence for
// cross-XCD visibility. Iter core byte-identical to R9 (proven); xtile
// staged ONCE per block and reused across all 3 passes; squash spread over
// all 256 blocks (80 outputs each). Atomic-S ruled out (R8: 32B fabric
// transactions, 84 MB/pass).
// b-logit algebra: b after t iters = u.(v0+..+v_{t-1}) (b starts at 0).
//
// ws: sp[128*10*128*16] v0T[20480] vsumT[20480] bars[5*32 u32]

#define B_ 128
#define J_ 10
#define K_ 1152
#define M_ 16
#define I_ 8
#define KT 9
#define NKT (K_ / KT)        // 128 k-tiles
#define RW (K_ * I_)         // 9216 floats per x batch-row
#define SVEC (J_ * B_ * M_)  // 20480 floats per fold-slice of sp
#define NBLK 256

// ---------- lightweight grid barrier (one poller per block) ------------------
// base[0] = arrive counter, base[16] = generation flag (separate 64B lines).
// Single-use per pair: last arriver sets gen=1 (release); others acquire-poll.
__device__ __forceinline__ void gbar(unsigned* base) {
    __syncthreads();                      // all block stores drained (vmcnt 0)
    if (threadIdx.x == 0) {
        __threadfence();                  // release: flush XCD L2 to coherent point
        const unsigned arrived =
            __hip_atomic_fetch_add(base, 1u, __ATOMIC_ACQ_REL,
                                   __HIP_MEMORY_SCOPE_AGENT) + 1u;
        if (arrived == NBLK) {
            __hip_atomic_store(base + 16, 1u, __ATOMIC_RELEASE,
                               __HIP_MEMORY_SCOPE_AGENT);
        } else {
            while (__hip_atomic_load(base + 16, __ATOMIC_ACQUIRE,
                                     __HIP_MEMORY_SCOPE_AGENT) == 0u)
                __builtin_amdgcn_s_sleep(2);
        }
        __threadfence();                  // acquire: invalidate stale L1/L2
    }
    __syncthreads();
}

// ---------- one routing pass (phase) -----------------------------------------
// MODE 0: c == 1 (iteration 0; 0.1 folded into squash<0>)
// MODE 1: c = softmax_j(u . vin); s = sum_k c*u (u stays in registers)
// Wave = output capsule j (10 waves), lane = batch b (64). xtile pre-staged.
template <int MODE>
__device__ __forceinline__ void route_pass(
    const float* __restrict__ xtile, float (* __restrict__ earr)[J_ * 64],
    const float* __restrict__ Ws, const float* __restrict__ vinT,
    float* __restrict__ sp, int kt, int j, int bl, int b)
{
    float v[M_], s[M_];
#pragma unroll
    for (int m = 0; m < M_; ++m) s[m] = 0.f;
    if (MODE == 1) {
        const float4* vp = (const float4*)(vinT + ((size_t)j * B_ + b) * M_);
#pragma unroll
        for (int q = 0; q < 4; ++q) {
            const float4 w = vp[q];
            v[4*q] = w.x; v[4*q+1] = w.y; v[4*q+2] = w.z; v[4*q+3] = w.w;
        }
    }

    for (int kk = 0; kk < KT; ++kk) {
        float xr[I_];
#pragma unroll
        for (int i = 0; i < I_; ++i) xr[i] = xtile[(kk * I_ + i) * 64 + bl];

        const float* w = Ws + ((size_t)j * K_ + kt * KT + kk) * (M_ * I_);  // uniform -> s_load
        float u[M_];
#pragma unroll
        for (int m = 0; m < M_; ++m) {
            float a = 0.f;
#pragma unroll
            for (int i = 0; i < I_; ++i) a += w[m * I_ + i] * xr[i];
            u[m] = a;
        }

        if (MODE == 1) {
            float lg = 0.f;
#pragma unroll
            for (int m = 0; m < M_; ++m) lg += u[m] * v[m];
            const float e = __expf(lg);
            earr[kk & 1][j * 64 + bl] = e;
            __syncthreads();   // one barrier/k; ping-pong makes reuse race-free
            float den = 0.f;
#pragma unroll
            for (int jj = 0; jj < J_; ++jj) den += earr[kk & 1][jj * 64 + bl];
            const float c = __fdividef(e, den);
#pragma unroll
            for (int m = 0; m < M_; ++m) s[m] += c * u[m];
        } else {
#pragma unroll
            for (int m = 0; m < M_; ++m) s[m] += u[m];
        }
    }

    float4* o = (float4*)(sp + (((size_t)kt * J_ + j) * B_ + b) * M_);
#pragma unroll
    for (int q = 0; q < 4; ++q) {
        float4 w;
        w.x = s[4*q]; w.y = s[4*q+1]; w.z = s[4*q+2]; w.w = s[4*q+3];
        o[q] = w;
    }
}

// ---------- squash phase: 80 outputs per block, 8 threads per output ---------
// SM 0: v0T = squash(0.1*S)  SM 1: vsumT = v0T + squash(S)  SM 2: out = squash(S)
template <int SM>
__device__ __forceinline__ void squash_phase(
    const float* __restrict__ sp, const float* __restrict__ v0T,
    float* __restrict__ dst, float* __restrict__ red, int bid, int t)
{
    const int o = t >> 3;                 // output within block, 0..79
    const int e = t & 7;                  // slice-eighth
    const int g = bid * 80 + o;           // g = (j*128+b)*16+m
    const float* p = sp + (size_t)(g >> 4) * M_ + (g & 15);
    float S = 0.f;
#pragma unroll
    for (int tt = e * 16; tt < e * 16 + 16; ++tt)
        S += p[(size_t)tt * SVEC];
    S += __shfl_xor(S, 1, 64);
    S += __shfl_xor(S, 2, 64);
    S += __shfl_xor(S, 4, 64);            // fold 8 partials (aligned 8-lane groups)
    if (e == 0) red[o] = S;
    __syncthreads();
    if (t < 80) {
        float S2 = red[t];
        if (SM == 0) S2 *= 0.1f;
        const int p16 = t & ~15;
        float sq = 0.f;
#pragma unroll
        for (int mm = 0; mm < M_; ++mm) {
            float r = red[p16 + mm];
            if (SM == 0) r *= 0.1f;
            sq += r * r;
        }
        const float n = sqrtf(sq);
        float v = S2 * (n / (1.f + sq));
        const int gg = bid * 80 + t;
        if (SM == 1) v += v0T[gg];
        if (SM == 2) {
            const int m = gg & 15, b = (gg >> 4) & 127, j = gg >> 11;
            dst[((size_t)b * J_ + j) * M_ + m] = v;   // standard [b][j][m]
        } else {
            dst[gg] = v;                               // vT layout
        }
    }
    __syncthreads();
}

// ---------- the single persistent kernel -------------------------------------
__global__ __launch_bounds__(640)
void persist_kernel(const float* __restrict__ x, const float* __restrict__ Ws,
                    float* __restrict__ sp, float* __restrict__ v0T,
                    float* __restrict__ vsumT, float* __restrict__ out,
                    unsigned* __restrict__ bars)
{
    __shared__ float xtile[KT * I_ * 64];    // 72 rows x 64 b = 18 KB
    __shared__ float earr[2][J_ * 64];
    __shared__ float red[80];
    const int t   = threadIdx.x;
    const int bid = blockIdx.x;
    const int bl  = t & 63;
    const int j   = __builtin_amdgcn_readfirstlane(t >> 6);  // wave-uniform j
    const int kt  = bid >> 1, bg = bid & 1;
    const int b   = bg * 64 + bl;

    // ---- stage + transpose x[bg*64..+64)[kt*72..+72) ONCE (reused 3 passes)
    {
        const float4* x4 = (const float4*)x;          // row stride RW/4 = 2304
        for (int idx = t; idx < 64 * 18; idx += 640) {
            const int bb = idx / 18, q = idx % 18;    // q = float4 within row
            const float4 w = x4[(size_t)(bg * 64 + bb) * (RW / 4) + kt * 18 + q];
            xtile[(q * 4 + 0) * 64 + bb] = w.x;
            xtile[(q * 4 + 1) * 64 + bb] = w.y;
            xtile[(q * 4 + 2) * 64 + bb] = w.z;
            xtile[(q * 4 + 3) * 64 + bb] = w.w;
        }
    }
    __syncthreads();

    route_pass<0>(xtile, earr, Ws, nullptr, sp, kt, j, bl, b);
    gbar(bars + 0 * 32);
    squash_phase<0>(sp, nullptr, v0T, red, bid, t);
    gbar(bars + 1 * 32);
    route_pass<1>(xtile, earr, Ws, v0T, sp, kt, j, bl, b);
    gbar(bars + 2 * 32);
    squash_phase<1>(sp, v0T, vsumT, red, bid, t);
    gbar(bars + 3 * 32);
    route_pass<1>(xtile, earr, Ws, vsumT, sp, kt, j, bl, b);
    gbar(bars + 4 * 32);
    squash_phase<2>(sp, nullptr, out, red, bid, t);
}

extern "C" void kernel_launch(void* const* d_in, const int* in_sizes, int n_in,
                              void* d_out, int out_size, void* d_ws, size_t ws_size,
                              hipStream_t stream) {
    const float* x  = (const float*)d_in[0];   // [128][1152][8]
    const float* Ws = (const float*)d_in[1];   // [10][1152][16][8]
    float* out = (float*)d_out;                // [128][10][16]

    float* sp    = (float*)d_ws;                           // 2,621,440 floats
    float* v0T   = sp + (size_t)NKT * SVEC;                //    20,480
    float* vsumT = v0T + SVEC;                             //    20,480
    unsigned* bars = (unsigned*)(vsumT + SVEC);            // 5*32 u32 (poisoned -> memset)

    hipMemsetAsync(bars, 0, 5 * 32 * sizeof(unsigned), stream);

    void* args[] = { (void*)&x, (void*)&Ws, (void*)&sp, (void*)&v0T,
                     (void*)&vsumT, (void*)&out, (void*)&bars };
    hipLaunchCooperativeKernel((const void*)persist_kernel, dim3(NBLK), dim3(640),
                               args, 0, stream);
}

// Round 7
// 140.257 us; speedup vs baseline: 2.4954x; 2.4954x over previous
//
#include <hip/hip_runtime.h>

// SemanticCaps dynamic routing, fp32. B=128, J=10, K=1152, M=16, I=8.
// R11 = R9 skeleton (best: 137.6 µs) with the iter stall fix:
//  (a) u-compute software-pipelined across the softmax barrier: k+1's
//      scalar Ws loads + FMAs execute in k's barrier-wait window (the
//      scalar-chunk stall chain was serializing in front of the barrier).
//  (b) KT 9->6: grid (192,2)=384 blocks -> 1.5 blocks/CU, so a second
//      resident block hides residual stalls (costs +5 MB sp round-trip).
// Grid-sync primitives are dead: device-scope atomics serialize at ~70-200ns
// each at the fabric (R4/R10: barrier = 256 atomics ~= 55 µs; cg same, R3).
// Graph dispatch boundaries are ~2-4 µs — the cheap grid barrier.
// b-logit algebra: b after t iters = u.(v0+..+v_{t-1}) (b starts at 0).
//
// ws (floats): sp[192*10*128*16] v0T[20480] vsumT[20480]

#define B_ 128
#define J_ 10
#define K_ 1152
#define M_ 16
#define I_ 8
#define KT 6
#define NKT (K_ / KT)        // 192 k-tiles
#define RW (K_ * I_)         // 9216 floats per x batch-row
#define SVEC (J_ * B_ * M_)  // 20480 floats per fold-slice of sp
#define XT4 (KT * I_ / 4)    // 12 float4 per b-row of the x tile

// ---------- routing pass -----------------------------------------------------
// MODE 0: c == 1 (iteration 0; 0.1 folded into squash<0>)
// MODE 1: c = softmax_j(u . vin);  s = sum_k c*u
// Wave = output capsule j (10 waves), lane = batch b (64). Block stages its
// own 48x64 x-tile via LDS transpose. u double-buffered: u_next is computed
// BETWEEN the earr write and the barrier, so its scalar-load stall chain
// overlaps the barrier wait.
template <int MODE>
__global__ __launch_bounds__(640)
void iter_kernel(const float* __restrict__ x, const float* __restrict__ Ws,
                 const float* __restrict__ vinT, float* __restrict__ sp) {
    __shared__ float xtile[KT * I_ * 64];    // 48 rows x 64 b = 12 KB
    __shared__ float earr[2][J_ * 64];
    const int t  = threadIdx.x;
    const int bl = t & 63;
    const int j  = __builtin_amdgcn_readfirstlane(t >> 6);  // wave-uniform j
    const int kt = blockIdx.x, bg = blockIdx.y;
    const int b  = bg * 64 + bl;

    // ---- stage + transpose x[bg*64..+64)[kt*48 .. +48) -> xtile[f][bb] -----
    {
        const float4* x4 = (const float4*)x;          // row stride RW/4 = 2304
        for (int idx = t; idx < 64 * XT4; idx += 640) {
            const int bb = idx / XT4, q = idx % XT4;  // q = float4 within row
            const float4 w = x4[(size_t)(bg * 64 + bb) * (RW / 4) + kt * XT4 + q];
            xtile[(q * 4 + 0) * 64 + bb] = w.x;
            xtile[(q * 4 + 1) * 64 + bb] = w.y;
            xtile[(q * 4 + 2) * 64 + bb] = w.z;
            xtile[(q * 4 + 3) * 64 + bb] = w.w;
        }
    }

    float v[M_], s[M_];
#pragma unroll
    for (int m = 0; m < M_; ++m) s[m] = 0.f;
    if (MODE == 1) {
        const float4* vp = (const float4*)(vinT + ((size_t)j * B_ + b) * M_);
#pragma unroll
        for (int q = 0; q < 4; ++q) {
            const float4 w = vp[q];
            v[4*q] = w.x; v[4*q+1] = w.y; v[4*q+2] = w.z; v[4*q+3] = w.w;
        }
    }
    __syncthreads();   // x-tile ready

    const float* wb = Ws + ((size_t)j * K_ + (size_t)kt * KT) * (M_ * I_);

    // prologue: u for kk = 0
    float up[M_], un[M_];
    {
        float xr[I_];
#pragma unroll
        for (int i = 0; i < I_; ++i) xr[i] = xtile[i * 64 + bl];
#pragma unroll
        for (int m = 0; m < M_; ++m) {
            float a = 0.f;
#pragma unroll
            for (int i = 0; i < I_; ++i) a += wb[m * I_ + i] * xr[i];
            up[m] = a;
        }
    }

    for (int kk = 0; kk < KT; ++kk) {
        float e = 0.f;
        if (MODE == 1) {
            float lg = 0.f;
#pragma unroll
            for (int m = 0; m < M_; ++m) lg += up[m] * v[m];
            e = __expf(lg);
            earr[kk & 1][j * 64 + bl] = e;
        }

        // pipeline: k+1's scalar Ws loads + FMAs run in the barrier window
        if (kk + 1 < KT) {
            float xr[I_];
#pragma unroll
            for (int i = 0; i < I_; ++i)
                xr[i] = xtile[((kk + 1) * I_ + i) * 64 + bl];
            const float* w = wb + (kk + 1) * (M_ * I_);
#pragma unroll
            for (int m = 0; m < M_; ++m) {
                float a = 0.f;
#pragma unroll
                for (int i = 0; i < I_; ++i) a += w[m * I_ + i] * xr[i];
                un[m] = a;
            }
        }

        if (MODE == 1) {
            __syncthreads();   // one barrier/k; ping-pong makes reuse race-free
            float den = 0.f;
#pragma unroll
            for (int jj = 0; jj < J_; ++jj) den += earr[kk & 1][jj * 64 + bl];
            const float c = __fdividef(e, den);
#pragma unroll
            for (int m = 0; m < M_; ++m) s[m] += c * up[m];
        } else {
#pragma unroll
            for (int m = 0; m < M_; ++m) s[m] += up[m];
        }

        if (kk + 1 < KT) {
#pragma unroll
            for (int m = 0; m < M_; ++m) up[m] = un[m];
        }
    }

    float4* o = (float4*)(sp + (((size_t)kt * J_ + j) * B_ + b) * M_);
#pragma unroll
    for (int q = 0; q < 4; ++q) {
        float4 w;
        w.x = s[4*q]; w.y = s[4*q+1]; w.z = s[4*q+2]; w.w = s[4*q+3];
        o[q] = w;
    }
}

// ---------- squash: parallel fold of 192 tile-partials, emit v ---------------
// 320 blocks x 256 thr; 4 waves each fold 48 slices for 64 outputs, LDS fold,
// wave 0 does the m-shuffle norm + emit.
// SM 0: v0T = squash(0.1*S)  SM 1: vsumT = v0T + squash(S)  SM 2: out = squash(S)
template <int SM>
__global__ __launch_bounds__(256)
void squash_kernel(const float* __restrict__ sp, const float* __restrict__ v0T,
                   float* __restrict__ dst) {
    __shared__ float red[4][64];
    const int t  = threadIdx.x;
    const int l  = t & 63;
    const int wv = t >> 6;
    const int g  = blockIdx.x * 64 + l;   // g = (j*128+b)*16+m
    const int m = g & 15;
    const int b = (g >> 4) & 127;
    const int j = g >> 11;
    const float* p = sp + (size_t)((j * B_ + b) * M_ + m);
    float S = 0.f;
#pragma unroll 8
    for (int tt = wv * (NKT / 4); tt < (wv + 1) * (NKT / 4); ++tt)
        S += p[(size_t)tt * SVEC];
    red[wv][l] = S;
    __syncthreads();
    if (wv == 0) {
        S = red[0][l] + red[1][l] + red[2][l] + red[3][l];
        if (SM == 0) S *= 0.1f;
        float sq = S * S;
        sq += __shfl_xor(sq, 1, 64);
        sq += __shfl_xor(sq, 2, 64);
        sq += __shfl_xor(sq, 4, 64);
        sq += __shfl_xor(sq, 8, 64);      // sum over m within 16-lane group
        const float n = sqrtf(sq);
        float v = S * (n / (1.f + sq));
        if (SM == 1) v += v0T[g];
        if (SM == 2) dst[((size_t)b * J_ + j) * M_ + m] = v;   // standard [b][j][m]
        else         dst[g] = v;                                // vT layout
    }
}

extern "C" void kernel_launch(void* const* d_in, const int* in_sizes, int n_in,
                              void* d_out, int out_size, void* d_ws, size_t ws_size,
                              hipStream_t stream) {
    const float* x  = (const float*)d_in[0];   // [128][1152][8]
    const float* Ws = (const float*)d_in[1];   // [10][1152][16][8]
    float* out = (float*)d_out;                // [128][10][16]

    float* sp    = (float*)d_ws;                           // 3,932,160 floats
    float* v0T   = sp + (size_t)NKT * SVEC;                //    20,480
    float* vsumT = v0T + SVEC;                             //    20,480

    iter_kernel<0><<<dim3(NKT, 2), 640, 0, stream>>>(x, Ws, nullptr, sp);
    squash_kernel<0><<<320, 256, 0, stream>>>(sp, nullptr, v0T);

    iter_kernel<1><<<dim3(NKT, 2), 640, 0, stream>>>(x, Ws, v0T, sp);
    squash_kernel<1><<<320, 256, 0, stream>>>(sp, v0T, vsumT);

    iter_kernel<1><<<dim3(NKT, 2), 640, 0, stream>>>(x, Ws, vsumT, sp);
    squash_kernel<2><<<320, 256, 0, stream>>>(sp, nullptr, out);
}